// Round 1
// baseline (337.015 us; speedup 1.0000x reference)
//
#include <hip/hip_runtime.h>
#include <hip/hip_bf16.h>
#include <stdint.h>

typedef __attribute__((ext_vector_type(4))) float f32x4;
typedef __attribute__((ext_vector_type(8))) short s16x8;
typedef __attribute__((ext_vector_type(4))) short s16x4;

// XOR-swizzle of 16B-granule index within a row (involution on low 3 bits)
#define SWZ(g, row) ((((g) & ~7) | (((g) ^ ((row) & 7)) & 7)))

__device__ __forceinline__ unsigned short f2bf(float f) {
  unsigned u = __builtin_bit_cast(unsigned, f);
  u += 0x7fffu + ((u >> 16) & 1u);   // round-to-nearest-even
  return (unsigned short)(u >> 16);
}

__device__ __forceinline__ void gld16(const void* g, void* l) {
  __builtin_amdgcn_global_load_lds(
      (const __attribute__((address_space(1))) void*)g,
      (__attribute__((address_space(3))) void*)l, 16, 0, 0);
}

// ---------------------------------------------------------------- convert
__global__ void cvt_f32_to_bf16(const float* __restrict__ src,
                                unsigned short* __restrict__ dst, int n4) {
  int i = blockIdx.x * blockDim.x + threadIdx.x;
  if (i >= n4) return;
  float4 v = ((const float4*)src)[i];
  s16x4 o;
  o[0] = (short)f2bf(v.x); o[1] = (short)f2bf(v.y);
  o[2] = (short)f2bf(v.z); o[3] = (short)f2bf(v.w);
  ((s16x4*)dst)[i] = o;
}

// ---------------------------------------------------------------- GEMM C = A * Bt^T
// A: M x K bf16 row-major, Bt: N x K bf16 row-major. 128x128 tile, BK=64.
// 4 waves, each wave: 32 rows x 128 cols (2x8 frags of 16x16, mfma 16x16x32).
// EPI==0: plain f32 store to C (ld = N).
// EPI==1: QKV epilogue — rotary for q/k tiles, transposed-V write for v tiles.
template<int EPI>
__global__ __launch_bounds__(256) void gemm_bt(
    const unsigned short* __restrict__ A,
    const unsigned short* __restrict__ Bt,
    float* __restrict__ C, int N, int K,
    const float* __restrict__ cosT, const float* __restrict__ sinT,
    unsigned short* __restrict__ qOut, unsigned short* __restrict__ kOut,
    unsigned short* __restrict__ vtOut)
{
  __shared__ char smem[32768];   // A tile 16KB @0, B tile 16KB @16384 ([128][64] bf16)
  const int tid = (int)threadIdx.x;
  const int w  = tid >> 6, l = tid & 63;
  const int lg = l & 15, hg = l >> 4;
  const int bn0 = (int)blockIdx.x * 128, bm0 = (int)blockIdx.y * 128;

  f32x4 acc[2][8] = {};
  const int nkt = K >> 6;
  for (int kt = 0; kt < nkt; ++kt) {
    __syncthreads();
    // stage A+B tiles: rows of 64 bf16 = 128B = 8 granules; swizzled global src
    for (int i = 0; i < 4; ++i) {
      const int G = w * 256 + i * 64 + l;         // 0..1023
      const int row = G >> 3, g = G & 7;
      const int gs = SWZ(g, row);
      gld16((const char*)(A  + (size_t)(bm0 + row) * K + (size_t)kt * 64) + (gs << 4),
            smem + w * 4096 + i * 1024);
      gld16((const char*)(Bt + (size_t)(bn0 + row) * K + (size_t)kt * 64) + (gs << 4),
            smem + 16384 + w * 4096 + i * 1024);
    }
    asm volatile("s_waitcnt vmcnt(0)" ::: "memory");
    __syncthreads();
    for (int ks = 0; ks < 2; ++ks) {
      s16x8 af[2], bfr[8];
      for (int ai = 0; ai < 2; ++ai) {
        const int ra = w * 32 + ai * 16 + lg;
        const int gr = SWZ(4 * ks + hg, ra);
        af[ai] = *(const s16x8*)(smem + ra * 128 + (gr << 4));
      }
      for (int bi = 0; bi < 8; ++bi) {
        const int rb = bi * 16 + lg;
        const int gr = SWZ(4 * ks + hg, rb);
        bfr[bi] = *(const s16x8*)(smem + 16384 + rb * 128 + (gr << 4));
      }
      for (int ai = 0; ai < 2; ++ai)
        for (int bi = 0; bi < 8; ++bi)
          acc[ai][bi] = __builtin_amdgcn_mfma_f32_16x16x32_bf16(
              af[ai], bfr[bi], acc[ai][bi], 0, 0, 0);
    }
  }

  if constexpr (EPI == 0) {
    for (int ai = 0; ai < 2; ++ai)
      for (int bi = 0; bi < 8; ++bi) {
        const int col  = bn0 + bi * 16 + lg;
        const int row0 = bm0 + w * 32 + ai * 16 + hg * 4;
        for (int r = 0; r < 4; ++r)
          C[(size_t)(row0 + r) * N + col] = acc[ai][bi][r];
      }
  } else {
    // col o = t*2048 + h*128 + d ; this 128-col tile is exactly one (t,h)
    const int t = bn0 >> 11;
    const int h = (bn0 >> 7) & 15;
    if (t < 2) {
      unsigned short* dst = (t == 0) ? qOut : kOut;
      for (int ai = 0; ai < 2; ++ai)
        for (int bi = 0; bi < 4; ++bi)
          for (int r = 0; r < 4; ++r) {
            const int gr = bm0 + w * 32 + ai * 16 + hg * 4 + r;
            const int b = gr >> 11, s1 = gr & 2047;
            const int c0 = bi * 16 + lg;                 // d in [0,64)
            const float x1 = acc[ai][bi][r];
            const float x2 = acc[ai][bi + 4][r];
            const float cv = cosT[s1 * 64 + c0];
            const float sv = sinT[s1 * 64 + c0];
            const size_t base = ((((size_t)b * 16 + h) * 2048) + s1) * 128;
            dst[base + c0]      = f2bf(x1 * cv - x2 * sv);
            dst[base + c0 + 64] = f2bf(x2 * cv + x1 * sv);
          }
    } else {
      // V: write transposed Vt[b][h][d][s] (4 consecutive s packed per store)
      for (int ai = 0; ai < 2; ++ai)
        for (int bi = 0; bi < 8; ++bi) {
          const int gr0 = bm0 + w * 32 + ai * 16 + hg * 4;
          const int b = gr0 >> 11, s0 = gr0 & 2047;
          const int d = bi * 16 + lg;
          s16x4 pk;
          for (int r = 0; r < 4; ++r) pk[r] = (short)f2bf(acc[ai][bi][r]);
          *(s16x4*)(vtOut + ((((size_t)b * 16 + h) * 128) + d) * 2048 + s0) = pk;
        }
    }
  }
}

// ---------------------------------------------------------------- flash attention
// grid: 1024 blocks = (bh=32) x (qtile=32). 4 waves x 16 q-rows, KV tiles of 64.
// Swapped QK^T: mfma(A=K, B=Q) -> lane owns a full P-row (col = lane&15 = q-row).
__global__ __launch_bounds__(256) void attn_fwd(
    const unsigned short* __restrict__ Qp, const unsigned short* __restrict__ Kp,
    const unsigned short* __restrict__ Vt, unsigned short* __restrict__ AO)
{
  __shared__ char sK[16384];   // [64][128] bf16, 16 granules/row, swizzled
  __shared__ char sV[16384];   // [128][64] bf16 (Vt tile), 8 granules/row, swizzled
  __shared__ char sP[8192];    // per-wave [16][64] bf16, swizzled

  const int tid = (int)threadIdx.x, w = tid >> 6, l = tid & 63;
  const int lg = l & 15, hg = l >> 4;
  const int bid = (int)blockIdx.x;
  const int qt = bid & 31, bh = bid >> 5;
  const size_t qkBase = (size_t)bh * 2048 * 128;   // also Vt head base (128*2048)
  const int qw0 = qt * 64 + w * 16;

  // Q fragments (B-operand): lane holds q-row (l&15), feature 32*ks + 8*hg
  s16x8 qf[4];
  for (int ks = 0; ks < 4; ++ks)
    qf[ks] = *(const s16x8*)(Qp + qkBase + (size_t)(qw0 + lg) * 128 + ks * 32 + hg * 8);

  f32x4 acc_o[8] = {};
  float mrun = -1e30f, lrun = 0.f;
  const float scale = 0.08838834764831845f;   // 1/sqrt(128)
  const float L2E = 1.4426950408889634f;

  const int nkv = qt + 1;
  for (int kv = 0; kv < nkv; ++kv) {
    const int kv0 = kv * 64;
    __syncthreads();
    // stage K tile [64][128] and Vt tile [128][64], swizzled global sources
    for (int i = 0; i < 4; ++i) {
      const int G = w * 256 + i * 64 + l;          // 0..1023
      const int rk = G >> 4, gk = G & 15;
      const int gks = SWZ(gk, rk);
      gld16((const char*)(Kp + qkBase + (size_t)(kv0 + rk) * 128) + (gks << 4),
            sK + w * 4096 + i * 1024);
      const int rv = G >> 3, gv = G & 7;
      const int gvs = SWZ(gv, rv);
      gld16((const char*)(Vt + qkBase + (size_t)rv * 2048 + kv0) + (gvs << 4),
            sV + w * 4096 + i * 1024);
    }
    asm volatile("s_waitcnt vmcnt(0)" ::: "memory");
    __syncthreads();

    // QK^T (swapped): accs[kf] holds S^T frag: row=j (kv), col=i (q-row)
    f32x4 accs[4] = {};
    for (int ks = 0; ks < 4; ++ks)
      for (int kf = 0; kf < 4; ++kf) {
        const int row = kf * 16 + lg;
        const int g = SWZ(4 * ks + hg, row);
        s16x8 kfrag = *(const s16x8*)(sK + row * 256 + (g << 4));
        accs[kf] = __builtin_amdgcn_mfma_f32_16x16x32_bf16(kfrag, qf[ks], accs[kf], 0, 0, 0);
      }

    // online softmax; lane owns q-row (lg), 16 scores j = kv0 + 16kf + 4*hg + r
    const int qi = qw0 + lg;
    float p[4][4];
    float mt = -1e30f;
    for (int kf = 0; kf < 4; ++kf)
      for (int r = 0; r < 4; ++r) {
        const int j = kv0 + kf * 16 + hg * 4 + r;
        float s = accs[kf][r] * scale;
        s = (j > qi) ? -1e30f : s;
        p[kf][r] = s;
        mt = fmaxf(mt, s);
      }
    mt = fmaxf(mt, __shfl_xor(mt, 16));
    mt = fmaxf(mt, __shfl_xor(mt, 32));
    const float mnew = fmaxf(mrun, mt);
    const float alpha = exp2f((mrun - mnew) * L2E);
    float ls = 0.f;
    for (int kf = 0; kf < 4; ++kf)
      for (int r = 0; r < 4; ++r) {
        const float e = exp2f((p[kf][r] - mnew) * L2E);
        p[kf][r] = e; ls += e;
      }
    ls += __shfl_xor(ls, 16);
    ls += __shfl_xor(ls, 32);
    lrun = lrun * alpha + ls;
    mrun = mnew;

    // rescale O: acc_o rows are i' = hg*4+r -> fetch alpha from lane i'
    float ar[4];
    for (int r = 0; r < 4; ++r) ar[r] = __shfl(alpha, hg * 4 + r);
    for (int f = 0; f < 8; ++f)
      for (int r = 0; r < 4; ++r) acc_o[f][r] *= ar[r];

    // P -> LDS (bf16), row = q-row lg, logical col j = 16kf + 4*hg + r
    char* pw = sP + w * 2048;
    for (int kf = 0; kf < 4; ++kf) {
      const int j0 = kf * 16 + hg * 4;
      s16x4 pk;
      for (int r = 0; r < 4; ++r) pk[r] = (short)f2bf(p[kf][r]);
      const int g = SWZ(j0 >> 3, lg);
      *(s16x4*)(pw + lg * 128 + (g << 4) + ((j0 * 2) & 15)) = pk;
    }
    asm volatile("" ::: "memory");   // keep P writes before P reads (in-order DS)

    // PV: O[i][d] += P[i][j] * Vt[d][j]
    for (int jc = 0; jc < 2; ++jc) {
      const int gp = SWZ(hg + 4 * jc, lg);
      s16x8 pa = *(const s16x8*)(pw + lg * 128 + (gp << 4));
      for (int f = 0; f < 8; ++f) {
        const int rv = f * 16 + lg;
        const int gv = SWZ(hg + 4 * jc, rv);
        s16x8 vb = *(const s16x8*)(sV + rv * 128 + (gv << 4));
        acc_o[f] = __builtin_amdgcn_mfma_f32_16x16x32_bf16(pa, vb, acc_o[f], 0, 0, 0);
      }
    }
  }

  // normalize + store AO[b*2048+s][h*128+d] bf16
  float linv[4];
  for (int r = 0; r < 4; ++r) linv[r] = 1.0f / __shfl(lrun, hg * 4 + r);
  const int b = bh >> 4, h = bh & 15;
  for (int f = 0; f < 8; ++f) {
    const int d = h * 128 + f * 16 + lg;
    for (int r = 0; r < 4; ++r) {
      const int srow = qt * 64 + w * 16 + hg * 4 + r;
      AO[((size_t)(b * 2048 + srow)) * 2048 + d] = f2bf(acc_o[f][r] * linv[r]);
    }
  }
}

// ---------------------------------------------------------------- launch
extern "C" void kernel_launch(void* const* d_in, const int* in_sizes, int n_in,
                              void* d_out, int out_size, void* d_ws, size_t ws_size,
                              hipStream_t stream) {
  const float* x    = (const float*)d_in[0];
  const float* qkvw = (const float*)d_in[1];
  const float* ow   = (const float*)d_in[2];
  const float* cosT = (const float*)d_in[3];
  const float* sinT = (const float*)d_in[4];
  float* out = (float*)d_out;

  // workspace layout (elements of bf16): total 112 MB
  unsigned short* X16  = (unsigned short*)d_ws;        // 4096x2048
  unsigned short* W16  = X16  + (size_t)8388608;       // 6144x2048
  unsigned short* OW16 = W16  + (size_t)12582912;      // 2048x2048
  unsigned short* Qp   = OW16 + (size_t)4194304;       // [2][16][2048][128]
  unsigned short* Kp   = Qp   + (size_t)8388608;
  unsigned short* Vtp  = Kp   + (size_t)8388608;       // [2][16][128][2048]
  unsigned short* AO   = Vtp  + (size_t)8388608;       // 4096x2048

  cvt_f32_to_bf16<<<8192, 256, 0, stream>>>(x, X16, 2097152);
  cvt_f32_to_bf16<<<12288, 256, 0, stream>>>(qkvw, W16, 3145728);
  cvt_f32_to_bf16<<<4096, 256, 0, stream>>>(ow, OW16, 1048576);

  dim3 g1(48, 32);  // N=6144, M=4096
  gemm_bt<1><<<g1, 256, 0, stream>>>(X16, W16, nullptr, 6144, 2048,
                                     cosT, sinT, Qp, Kp, Vtp);

  attn_fwd<<<1024, 256, 0, stream>>>(Qp, Kp, Vtp, AO);

  dim3 g2(16, 32);  // N=2048, M=4096
  gemm_bt<0><<<g2, 256, 0, stream>>>(AO, OW16, out, 2048, 2048,
                                     nullptr, nullptr, nullptr, nullptr, nullptr);
}